// Round 2
// baseline (481.345 us; speedup 1.0000x reference)
//
#include <hip/hip_runtime.h>
#include <cstdint>

typedef unsigned short u16;
typedef short bh8 __attribute__((ext_vector_type(8)));
typedef float f32x4 __attribute__((ext_vector_type(4)));

#define EPSF 1.1920929e-07f
#define INV_SQRT2 0.70710678118654752440f

// ---------------- workspace layout (bytes) ----------------
static constexpr size_t OFF_XB   = 0;                        // 8192*2048*2 (x bf16; later thetaA bf16)
static constexpr size_t OFF_WCAT = 33554432;                 // [2304][2048] bf16 = 9437184
static constexpr size_t OFF_SC   = OFF_WCAT + 9175040;       // scales: inside wcat pad rows (2240..2303), 32KB
static constexpr size_t OFF_WOUT = OFF_WCAT + 9437184;       // 2048*2048*2
static constexpr size_t OFF_THBF = OFF_WOUT + 8388608;       // 8192*2048*2 (butterflyB out)
static constexpr size_t OFF_PHI  = OFF_THBF + 33554432;      // 8192*192*4
static constexpr size_t OFF_TRA  = OFF_PHI + 6291456;        // cosA + sinA
static constexpr size_t OFF_TRB  = OFF_TRA + 6291456;        // cosB + sinB

// ---------------- helpers ----------------
__device__ __forceinline__ uint32_t f2bf_rne(float f) {
  uint32_t u = __float_as_uint(f);
  u += 0x7fffu + ((u >> 16) & 1u);
  return u >> 16;
}

__device__ __forceinline__ void gload_lds16(const void* g, void* l) {
  __builtin_amdgcn_global_load_lds(
      (const __attribute__((address_space(1))) void*)g,
      (__attribute__((address_space(3))) void*)l, 16, 0, 0);
}

// ---------------- cast f32 -> bf16 ----------------
__global__ __launch_bounds__(256)
void cast_f32_bf16(const float* __restrict__ src, u16* __restrict__ dst, int n4) {
  int i = blockIdx.x * blockDim.x + threadIdx.x;
  int stride = gridDim.x * blockDim.x;
  for (; i < n4; i += stride) {
    float4 v = ((const float4*)src)[i];
    uint32_t a = __float_as_uint(v.x); a += 0x7fffu + ((a >> 16) & 1u);
    uint32_t b = __float_as_uint(v.y); b += 0x7fffu + ((b >> 16) & 1u);
    uint32_t c = __float_as_uint(v.z); c += 0x7fffu + ((c >> 16) & 1u);
    uint32_t d = __float_as_uint(v.w); d += 0x7fffu + ((d >> 16) & 1u);
    uint2 o;
    o.x = (a >> 16) | (b & 0xffff0000u);
    o.y = (c >> 16) | (d & 0xffff0000u);
    ((uint2*)dst)[i] = o;
  }
}

__global__ __launch_bounds__(256)
void zero_u16(u16* __restrict__ dst, int n) {
  int i = blockIdx.x * blockDim.x + threadIdx.x;
  int stride = gridDim.x * blockDim.x;
  for (; i < n; i += stride) dst[i] = 0;
}

// ---------------- deep-pipelined bf16 GEMM (NT): C[m,n] = sum_k A[m,k]*B[n,k] ----
// Tile 256x128, BK=32, 8 waves (4Mx2N), per-wave 64x64 out, K=2048 hardcoded.
// LDS: 3 buffers (A 16KB + B 8KB each) = 72KB; prefetch 2 tiles ahead;
// counted vmcnt(3) at every K-tile boundary (never 0 until tail).
// LDS cell(row,g) at (row&15)*16 + g*256 + (row>>4)*1024  -> frag read = contiguous 1KB/wave.
template<int SPLIT>
__global__ __launch_bounds__(512, 2)
void gemm_dp(const u16* __restrict__ A, const u16* __restrict__ B,
             float* __restrict__ C0, float* __restrict__ C1,
             int ntiles, int nwg) {
  __shared__ __align__(16) char ldsb[73728];
  const int tid  = threadIdx.x;
  const int w    = tid >> 6;
  const int lane = tid & 63;
  // bijective XCD swizzle (nwg % 8 == 0)
  const int cpx = nwg >> 3;
  const int wg  = (blockIdx.x & 7) * cpx + (blockIdx.x >> 3);
  const int mt = wg / ntiles, nt = wg % ntiles;
  const int wm = (w >> 1) << 6;          // 0,64,128,192 (rows)
  const int wn = (w & 1) << 6;           // 0,64 (cols)
  const int wmR = (w >> 1) << 2;         // wm>>4
  const int wnR = (w & 1) << 2;          // wn>>4
  const size_t Kb = 4096;                // K=2048 * 2B

  const char* Ab = (const char*)A + (size_t)mt * 256 * Kb;
  const char* Bb = (const char*)B + (size_t)nt * 128 * Kb;

  // staging decode: slot s -> row=(s>>6)*16+(s&15), kslot g=(s>>4)&3
  const int sA1 = 512 + tid;
  const int rA0 = ((tid >> 6) << 4) + (tid & 15);
  const int gA0 = ((tid >> 4) & 3) << 4;
  const int rA1 = ((sA1 >> 6) << 4) + (sA1 & 15);
  const int gA1 = ((sA1 >> 4) & 3) << 4;
  const char* srcA0 = Ab + (size_t)rA0 * Kb + gA0;
  const char* srcA1 = Ab + (size_t)rA1 * Kb + gA1;
  const char* srcB  = Bb + (size_t)rA0 * Kb + gA0;
  const int wB = w * 1024;               // wave-uniform LDS component (HW adds lane*16)
  const int lo = ((lane >> 4) << 8) + ((lane & 15) << 4);

  f32x4 acc[4][4] = {};

#define STAGE_A(tt, cc) do { \
    gload_lds16(srcA0 + (tt) * 64, ldsb + (cc) * 16384 + wB); \
    gload_lds16(srcA1 + (tt) * 64, ldsb + (cc) * 16384 + 8192 + wB); } while (0)
#define STAGE_B(tt, cc) \
    gload_lds16(srcB + (tt) * 64, ldsb + 49152 + (cc) * 8192 + wB)

  // prologue: stage tiles 0,1
  STAGE_A(0, 0); STAGE_B(0, 0);
  STAGE_A(1, 1); STAGE_B(1, 1);
  asm volatile("s_waitcnt vmcnt(3)" ::: "memory");
  __builtin_amdgcn_s_barrier();

  int c = 0;
  for (int t = 0; t < 64; ++t) {
    int c2 = c + 2; if (c2 >= 3) c2 -= 3;
    const char* Abase = ldsb + c * 16384;
    const char* Bbase = ldsb + 49152 + c * 8192;
    // ---- phase 1: stage A(t+2) | read a0,a1,b0..b3 | 8 MFMA ----
    if (t < 62) STAGE_A(t + 2, c2);
    bh8 a0 = *(const bh8*)(Abase + (wmR + 0) * 1024 + lo);
    bh8 a1 = *(const bh8*)(Abase + (wmR + 1) * 1024 + lo);
    bh8 b0 = *(const bh8*)(Bbase + (wnR + 0) * 1024 + lo);
    bh8 b1 = *(const bh8*)(Bbase + (wnR + 1) * 1024 + lo);
    bh8 b2 = *(const bh8*)(Bbase + (wnR + 2) * 1024 + lo);
    bh8 b3 = *(const bh8*)(Bbase + (wnR + 3) * 1024 + lo);
    __builtin_amdgcn_s_barrier();
    __builtin_amdgcn_s_setprio(1);
    acc[0][0] = __builtin_amdgcn_mfma_f32_16x16x32_bf16(a0, b0, acc[0][0], 0, 0, 0);
    acc[0][1] = __builtin_amdgcn_mfma_f32_16x16x32_bf16(a0, b1, acc[0][1], 0, 0, 0);
    acc[0][2] = __builtin_amdgcn_mfma_f32_16x16x32_bf16(a0, b2, acc[0][2], 0, 0, 0);
    acc[0][3] = __builtin_amdgcn_mfma_f32_16x16x32_bf16(a0, b3, acc[0][3], 0, 0, 0);
    acc[1][0] = __builtin_amdgcn_mfma_f32_16x16x32_bf16(a1, b0, acc[1][0], 0, 0, 0);
    acc[1][1] = __builtin_amdgcn_mfma_f32_16x16x32_bf16(a1, b1, acc[1][1], 0, 0, 0);
    acc[1][2] = __builtin_amdgcn_mfma_f32_16x16x32_bf16(a1, b2, acc[1][2], 0, 0, 0);
    acc[1][3] = __builtin_amdgcn_mfma_f32_16x16x32_bf16(a1, b3, acc[1][3], 0, 0, 0);
    __builtin_amdgcn_s_setprio(0);
    __builtin_amdgcn_s_barrier();
    // ---- phase 2: stage B(t+2) | read a2,a3 | 8 MFMA | boundary vmcnt ----
    if (t < 62) STAGE_B(t + 2, c2);
    bh8 a2 = *(const bh8*)(Abase + (wmR + 2) * 1024 + lo);
    bh8 a3 = *(const bh8*)(Abase + (wmR + 3) * 1024 + lo);
    __builtin_amdgcn_s_barrier();
    __builtin_amdgcn_s_setprio(1);
    acc[2][0] = __builtin_amdgcn_mfma_f32_16x16x32_bf16(a2, b0, acc[2][0], 0, 0, 0);
    acc[2][1] = __builtin_amdgcn_mfma_f32_16x16x32_bf16(a2, b1, acc[2][1], 0, 0, 0);
    acc[2][2] = __builtin_amdgcn_mfma_f32_16x16x32_bf16(a2, b2, acc[2][2], 0, 0, 0);
    acc[2][3] = __builtin_amdgcn_mfma_f32_16x16x32_bf16(a2, b3, acc[2][3], 0, 0, 0);
    acc[3][0] = __builtin_amdgcn_mfma_f32_16x16x32_bf16(a3, b0, acc[3][0], 0, 0, 0);
    acc[3][1] = __builtin_amdgcn_mfma_f32_16x16x32_bf16(a3, b1, acc[3][1], 0, 0, 0);
    acc[3][2] = __builtin_amdgcn_mfma_f32_16x16x32_bf16(a3, b2, acc[3][2], 0, 0, 0);
    acc[3][3] = __builtin_amdgcn_mfma_f32_16x16x32_bf16(a3, b3, acc[3][3], 0, 0, 0);
    __builtin_amdgcn_s_setprio(0);
    if (t < 62) asm volatile("s_waitcnt vmcnt(3)" ::: "memory");
    else        asm volatile("s_waitcnt vmcnt(0)" ::: "memory");
    __builtin_amdgcn_s_barrier();
    c = (c == 2) ? 0 : c + 1;
  }
#undef STAGE_A
#undef STAGE_B

  // epilogue: C/D layout col=lane&15, row=(lane>>4)*4+reg (m89-verified)
  const int crow0 = mt * 256 + wm + ((lane >> 4) << 2);
  const int ccol0 = nt * 128 + wn + (lane & 15);
  #pragma unroll
  for (int m = 0; m < 4; ++m) {
    #pragma unroll
    for (int n = 0; n < 4; ++n) {
      int gn = ccol0 + n * 16;
      #pragma unroll
      for (int r = 0; r < 4; ++r) {
        int gm = crow0 + m * 16 + r;
        if (SPLIT) {
          if (gn < 2048)      C0[(size_t)gm * 2048 + gn] = acc[m][n][r];
          else if (gn < 2240) C1[(size_t)gm * 192 + (gn - 2048)] = acc[m][n][r];
        } else {
          C0[(size_t)gm * 2048 + gn] = acc[m][n][r];
        }
      }
    }
  }
}

// ---------------- RMSNorm scales only (row of 2048 f32 -> 1 f32) ----------------
__global__ __launch_bounds__(256)
void rmsnorm_scales(const float* __restrict__ th, float* __restrict__ sc) {
  const int row = blockIdx.x;
  const int tid = threadIdx.x;
  const float* p = th + (size_t)row * 2048;
  float4 a = ((const float4*)p)[tid];
  float4 b = ((const float4*)p)[tid + 256];
  float ss = a.x*a.x + a.y*a.y + a.z*a.z + a.w*a.w
           + b.x*b.x + b.y*b.y + b.z*b.z + b.w*b.w;
  #pragma unroll
  for (int o = 32; o > 0; o >>= 1) ss += __shfl_down(ss, o);
  __shared__ float red[4];
  if ((tid & 63) == 0) red[tid >> 6] = ss;
  __syncthreads();
  if (tid == 0) {
    float tot = red[0] + red[1] + red[2] + red[3];
    sc[row] = rsqrtf(tot * (1.0f / 2048.0f) + EPSF);
  }
}

// ---------------- phi: RMSNorm(192) + cos/sin tables ----------------
__global__ __launch_bounds__(64)
void phi_pass(const float* __restrict__ phiraw,
              float* __restrict__ trigA, float* __restrict__ trigB) {
  const int row = blockIdx.x;  // b*4096 + t
  const int tid = threadIdx.x;
  const float* pr = phiraw + (size_t)row * 192;
  float v0 = pr[tid], v1 = pr[tid + 64], v2 = pr[tid + 128];
  float ss = v0 * v0 + v1 * v1 + v2 * v2;
  #pragma unroll
  for (int o = 32; o > 0; o >>= 1) ss += __shfl_down(ss, o);
  ss = __shfl(ss, 0);
  const float sc = rsqrtf(ss * (1.0f / 192.0f) + EPSF);
  const int b = row >> 12, t = row & 4095;
  const int q = t >> 6, r = t & 63;
  float v[3] = {v0, v1, v2};
  #pragma unroll
  for (int j = 0; j < 3; ++j) {
    int e = j * 64 + tid;
    int l = e >> 4, h = e & 15;
    float ph = v[j] * sc;
    float sn, cs;
    sincosf(ph, &sn, &cs);
    if (l < 6) {
      size_t idx = ((size_t)((b * 16 + h) * 6 + l)) * 4096 + t;
      trigA[idx] = cs; trigA[idx + 786432] = sn;
    } else {
      size_t idx = ((size_t)((b * 16 + h) * 6 + (l - 6))) * 4096 + (size_t)(r * 64 + q);
      trigB[idx] = cs; trigB[idx + 786432] = sn;
    }
  }
}

// ---------------- butterfly levels 0..5 (scale applied on load) ----------------
__global__ __launch_bounds__(512)
void butterflyA(const float* __restrict__ in, u16* __restrict__ outb,
                const float* __restrict__ trigA, const float* __restrict__ scales) {
  __shared__ float L[512 * 32];
  const int tc = blockIdx.x, ec = blockIdx.y, b = blockIdx.z;
  const int tid = threadIdx.x;
  const int t0 = tc * 449;
  const int e0 = ec * 32;
  const int h = e0 >> 7;
  const int pr = tid >> 3;
  const int c4 = (tid & 7) << 2;

  #pragma unroll
  for (int s = 0; s < 8; ++s) {
    int p = pr + s * 64;
    int t = t0 - 63 + p;
    float4 v = make_float4(0.f, 0.f, 0.f, 0.f);
    if (t >= 0 && t < 4096) {
      v = *(const float4*)&in[((size_t)(b * 4096 + t)) * 2048 + e0 + c4];
      float scl = scales[b * 4096 + t];
      v.x *= scl; v.y *= scl; v.z *= scl; v.w *= scl;
    }
    *(float4*)&L[p * 32 + c4] = v;
  }
  __syncthreads();

  for (int l = 0; l < 6; ++l) {
    const int step = 1 << l;
    const float* cosT = trigA + ((size_t)((b * 16 + h) * 6 + l)) * 4096;
    const float* sinT = cosT + 786432;
    float4 nv[8];
    #pragma unroll
    for (int s = 0; s < 8; ++s) {
      int p = pr + s * 64;
      int t = t0 - 63 + p;
      float4 cur = *(const float4*)&L[p * 32 + c4];
      float4 prev = make_float4(0.f, 0.f, 0.f, 0.f);
      if (p >= step) prev = *(const float4*)&L[(p - step) * 32 + c4];
      float cs = 0.f, sn = 0.f;
      if (t >= 0 && t < 4096) { cs = cosT[t]; sn = sinT[t]; }
      nv[s].x = (cs * cur.x + sn * prev.x) * INV_SQRT2;
      nv[s].y = (cs * cur.y + sn * prev.y) * INV_SQRT2;
      nv[s].z = (cs * cur.z + sn * prev.z) * INV_SQRT2;
      nv[s].w = (cs * cur.w + sn * prev.w) * INV_SQRT2;
    }
    __syncthreads();
    #pragma unroll
    for (int s = 0; s < 8; ++s) {
      int p = pr + s * 64;
      *(float4*)&L[p * 32 + c4] = nv[s];
    }
    __syncthreads();
  }

  #pragma unroll
  for (int s = 0; s < 8; ++s) {
    int p = pr + s * 64;
    int t = t0 - 63 + p;
    if (p >= 63 && t < 4096) {
      float4 v = *(const float4*)&L[p * 32 + c4];
      uint32_t a = f2bf_rne(v.x), bb = f2bf_rne(v.y), c = f2bf_rne(v.z), d = f2bf_rne(v.w);
      uint2 o;
      o.x = a | (bb << 16);
      o.y = c | (d << 16);
      *(uint2*)&outb[((size_t)(b * 4096 + t)) * 2048 + e0 + c4] = o;
    }
  }
}

// ---------------- butterfly levels 6..11 ----------------
__global__ __launch_bounds__(256)
void butterflyB(const u16* __restrict__ in, u16* __restrict__ outb,
                const float* __restrict__ trigB) {
  __shared__ float L[64 * 128];
  const int r = blockIdx.x, h = blockIdx.y, b = blockIdx.z;
  const int tid = threadIdx.x;
  const int qr = tid >> 5;
  const int d4 = (tid & 31) << 2;

  #pragma unroll
  for (int s = 0; s < 8; ++s) {
    int q = qr + s * 8;
    int t = q * 64 + r;
    uint2 o = *(const uint2*)&in[((size_t)(b * 4096 + t)) * 2048 + h * 128 + d4];
    float4 v;
    v.x = __uint_as_float((o.x & 0xffffu) << 16);
    v.y = __uint_as_float(o.x & 0xffff0000u);
    v.z = __uint_as_float((o.y & 0xffffu) << 16);
    v.w = __uint_as_float(o.y & 0xffff0000u);
    *(float4*)&L[q * 128 + d4] = v;
  }
  __syncthreads();

  for (int l = 0; l < 6; ++l) {
    const int qs = 1 << l;
    const float* cosT = trigB + ((size_t)((b * 16 + h) * 6 + l)) * 4096 + r * 64;
    const float* sinT = cosT + 786432;
    float4 nv[8];
    #pragma unroll
    for (int s = 0; s < 8; ++s) {
      int q = qr + s * 8;
      float4 cur = *(const float4*)&L[q * 128 + d4];
      float4 prev = make_float4(0.f, 0.f, 0.f, 0.f);
      if (q >= qs) prev = *(const float4*)&L[(q - qs) * 128 + d4];
      float cs = cosT[q], sn = sinT[q];
      nv[s].x = (cs * cur.x + sn * prev.x) * INV_SQRT2;
      nv[s].y = (cs * cur.y + sn * prev.y) * INV_SQRT2;
      nv[s].z = (cs * cur.z + sn * prev.z) * INV_SQRT2;
      nv[s].w = (cs * cur.w + sn * prev.w) * INV_SQRT2;
    }
    __syncthreads();
    #pragma unroll
    for (int s = 0; s < 8; ++s) {
      int q = qr + s * 8;
      *(float4*)&L[q * 128 + d4] = nv[s];
    }
    __syncthreads();
  }

  #pragma unroll
  for (int s = 0; s < 8; ++s) {
    int q = qr + s * 8;
    int t = q * 64 + r;
    float4 v = *(const float4*)&L[q * 128 + d4];
    uint32_t a = f2bf_rne(v.x), bb = f2bf_rne(v.y), c = f2bf_rne(v.z), d = f2bf_rne(v.w);
    uint2 o;
    o.x = a | (bb << 16);
    o.y = c | (d << 16);
    *(uint2*)&outb[((size_t)(b * 4096 + t)) * 2048 + h * 128 + d4] = o;
  }
}

// ---------------- launch ----------------
extern "C" void kernel_launch(void* const* d_in, const int* in_sizes, int n_in,
                              void* d_out, int out_size, void* d_ws, size_t ws_size,
                              hipStream_t stream) {
  const float* x    = (const float*)d_in[0];
  const float* Wtok = (const float*)d_in[1];
  const float* Wlvl = (const float*)d_in[2];
  const float* Wout = (const float*)d_in[3];

  char* ws = (char*)d_ws;
  u16*   xb     = (u16*)(ws + OFF_XB);
  u16*   wcat   = (u16*)(ws + OFF_WCAT);
  u16*   woutb  = (u16*)(ws + OFF_WOUT);
  u16*   thbfA  = (u16*)(ws + OFF_XB);     // alias: x_bf16 dead after gemm1
  u16*   thbfB  = (u16*)(ws + OFF_THBF);
  float* scales = (float*)(ws + OFF_SC);   // inside wcat zero-pad rows (dead after gemm1)
  float* phiraw = (float*)(ws + OFF_PHI);
  float* trigA  = (float*)(ws + OFF_TRA);
  float* trigB  = (float*)(ws + OFF_TRB);
  float* out    = (float*)d_out;

  // 1. casts (f32 -> bf16)
  cast_f32_bf16<<<2048, 256, 0, stream>>>(x, xb, 4194304);
  cast_f32_bf16<<<1024, 256, 0, stream>>>(Wtok, wcat, 1048576);
  cast_f32_bf16<<<384, 256, 0, stream>>>(Wlvl, wcat + (size_t)2048 * 2048, 98304);
  zero_u16<<<128, 256, 0, stream>>>(wcat + (size_t)2240 * 2048, 131072);
  cast_f32_bf16<<<1024, 256, 0, stream>>>(Wout, woutb, 1048576);

  // 2. GEMM1 (fused theta+phi): [8192,2048] x [2304,2048]^T, 32x18=576 blocks
  gemm_dp<1><<<576, 512, 0, stream>>>(xb, wcat, out, phiraw, 18, 576);

  // 3. RMSNorm scales only (applied inside butterflyA)
  rmsnorm_scales<<<8192, 256, 0, stream>>>(out, scales);

  // 4. phi: RMSNorm + trig tables
  phi_pass<<<8192, 64, 0, stream>>>(phiraw, trigA, trigB);

  // 5. butterfly levels 0..5 (f32+scale in, bf16 out)
  butterflyA<<<dim3(10, 64, 2), 512, 0, stream>>>(out, thbfA, trigA, scales);

  // 6. butterfly levels 6..11
  butterflyB<<<dim3(64, 16, 2), 256, 0, stream>>>(thbfA, thbfB, trigB);

  // 7. GEMM3: theta_bf16 x W_out^T -> d_out, 32x16=512 blocks
  gemm_dp<0><<<512, 512, 0, stream>>>(thbfB, woutb, out, nullptr, 16, 512);
}

// Round 4
// 461.567 us; speedup vs baseline: 1.0429x; 1.0429x over previous
//
#include <hip/hip_runtime.h>
#include <cstdint>

typedef unsigned short u16;
typedef short bh8 __attribute__((ext_vector_type(8)));
typedef float f32x4 __attribute__((ext_vector_type(4)));

#define EPSF 1.1920929e-07f
#define INV_SQRT2 0.70710678118654752440f
#define SINOFF 1572864

// ---------------- workspace layout (bytes) ----------------
static constexpr size_t OFF_XB   = 0;                        // x bf16 33554432; later thetaA bf16
static constexpr size_t OFF_WCAT = 33554432;                 // [2304][2048] bf16 = 9437184
static constexpr size_t OFF_WOUT = OFF_WCAT + 9437184;       // 8388608
static constexpr size_t OFF_THBF = OFF_WOUT + 8388608;       // 33554432: phiq (25.1MB, dead after phi_pass) then theta_final bf16
static constexpr size_t OFF_TRIG = OFF_THBF + 33554432;      // 12582912 (cos 1572864 f32 + sin)
static constexpr size_t OFF_SSQ  = OFF_TRIG + 12582912;      // 32768
// total 97550336 (< 99MB proven in round 1)

// ---------------- helpers ----------------
__device__ __forceinline__ uint32_t f2bf_rne(float f) {
  uint32_t u = __float_as_uint(f);
  u += 0x7fffu + ((u >> 16) & 1u);
  return u >> 16;
}

__device__ __forceinline__ void gload_lds16(const void* g, void* l) {
  __builtin_amdgcn_global_load_lds(
      (const __attribute__((address_space(1))) void*)g,
      (__attribute__((address_space(3))) void*)l, 16, 0, 0);
}

// ---------------- zero f32 (float4) ----------------
__global__ __launch_bounds__(256)
void zero_f32(float4* __restrict__ p, int n4) {
  int i = blockIdx.x * blockDim.x + threadIdx.x;
  if (i < n4) p[i] = make_float4(0.f, 0.f, 0.f, 0.f);
}

// ---------------- cast f32 -> bf16 ----------------
__global__ __launch_bounds__(256)
void cast_f32_bf16(const float* __restrict__ src, u16* __restrict__ dst, int n4) {
  int i = blockIdx.x * blockDim.x + threadIdx.x;
  int stride = gridDim.x * blockDim.x;
  for (; i < n4; i += stride) {
    float4 v = ((const float4*)src)[i];
    uint32_t a = __float_as_uint(v.x); a += 0x7fffu + ((a >> 16) & 1u);
    uint32_t b = __float_as_uint(v.y); b += 0x7fffu + ((b >> 16) & 1u);
    uint32_t c = __float_as_uint(v.z); c += 0x7fffu + ((c >> 16) & 1u);
    uint32_t d = __float_as_uint(v.w); d += 0x7fffu + ((d >> 16) & 1u);
    uint2 o;
    o.x = (a >> 16) | (b & 0xffff0000u);
    o.y = (c >> 16) | (d & 0xffff0000u);
    ((uint2*)dst)[i] = o;
  }
}

// ---------------- bf16 GEMM (NT), 256x256 tile, BK=32, triple-buffer LDS ----------------
// 8 waves (2M x 4N), per-wave 128x64 output (FLOP/LDS-byte = 42.7).
// Per K-tile: 4 gload_lds (stage t+2), 12 ds_read_b128, 32 MFMA, 1 counted vmcnt(4), 1 barrier.
// Buffer rotation tile%3 => staged buffer never readable concurrently (race-free by construction).
// LDS cell layout: cell c = rb*64 + g*16 + r15 (row=rb*16+r15, kbytes g*16) => frag read = contiguous 1KB.
// MODE 0: plain (GEMM3).  MODE 1: GEMM1 — wg<256: theta (C=f32 out + sumsq atomics); wg>=256: phi split-K partials.
template<int MODE>
__global__ __launch_bounds__(512, 2)
void gemm8(const u16* __restrict__ A, const u16* __restrict__ B,
           float* __restrict__ C, float* __restrict__ phiq,
           float* __restrict__ sumsq, int nwg) {
  __shared__ __align__(16) char ldsb[98304];
  const int tid  = threadIdx.x;
  const int w    = tid >> 6;
  const int lane = tid & 63;
  // bijective XCD swizzle (nwg % 8 == 0)
  const int cpx = nwg >> 3;
  const int wg  = ((int)blockIdx.x & 7) * cpx + ((int)blockIdx.x >> 3);

  int mt, nt, t0, TT, kq = 0;
  bool isphi = false;
  if (MODE == 0) { mt = wg >> 3; nt = wg & 7; t0 = 0; TT = 64; }
  else {
    if (wg < 256) { mt = wg >> 3; nt = wg & 7; t0 = 0; TT = 64; }
    else { int idx = wg - 256; mt = idx >> 2; kq = idx & 3; nt = 8; t0 = kq * 16; TT = 16; isphi = true; }
  }
  const int wr = w >> 2, wc = w & 3;

  const char* Ab = (const char*)A + (size_t)mt * 256 * 4096;
  const char* Bb = (const char*)B + (size_t)nt * 256 * 4096;

  // staging source decode (cell c = j*512 + tid)
  const int row0 = ((tid >> 6) << 4) + (tid & 15);
  const int g16  = ((tid >> 4) & 3) << 4;
  const char* sA0 = Ab + (size_t)row0 * 4096 + g16 + (size_t)t0 * 64;
  const char* sA1 = sA0 + 128 * 4096;
  const char* sB0 = Bb + (size_t)row0 * 4096 + g16 + (size_t)t0 * 64;
  const char* sB1 = sB0 + 128 * 4096;
  const int wB = w * 1024;             // wave-uniform LDS base component (HW adds lane*16)
  const int lo16 = lane * 16;

  f32x4 acc[8][4] = {};

#define STG(tt, cb) do { \
    gload_lds16(sA0 + (tt) * 64, ldsb + (cb) * 32768 + wB); \
    gload_lds16(sA1 + (tt) * 64, ldsb + (cb) * 32768 + 8192 + wB); \
    gload_lds16(sB0 + (tt) * 64, ldsb + (cb) * 32768 + 16384 + wB); \
    gload_lds16(sB1 + (tt) * 64, ldsb + (cb) * 32768 + 24576 + wB); } while (0)

  STG(0, 0);
  STG(1, 1);
  asm volatile("s_waitcnt vmcnt(4)" ::: "memory");
  __builtin_amdgcn_s_barrier();

  int c = 0;
  for (int t = 0; t < TT; ++t) {
    int c2 = c + 2; if (c2 >= 3) c2 -= 3;
    if (t + 2 < TT) STG(t + 2, c2);
    const char* A_ = ldsb + c * 32768 + wr * 8192;
    const char* B_ = ldsb + c * 32768 + 16384 + wc * 4096;
    bh8 bf[4], af[8];
    #pragma unroll
    for (int n = 0; n < 4; ++n) bf[n] = *(const bh8*)(B_ + n * 1024 + lo16);
    #pragma unroll
    for (int m = 0; m < 8; ++m) af[m] = *(const bh8*)(A_ + m * 1024 + lo16);
    __builtin_amdgcn_s_setprio(1);
    #pragma unroll
    for (int m = 0; m < 8; ++m)
      #pragma unroll
      for (int n = 0; n < 4; ++n)
        acc[m][n] = __builtin_amdgcn_mfma_f32_16x16x32_bf16(af[m], bf[n], acc[m][n], 0, 0, 0);
    __builtin_amdgcn_s_setprio(0);
    if (t + 1 < TT) {
      if (t + 2 < TT) asm volatile("s_waitcnt vmcnt(4)" ::: "memory");
      else            asm volatile("s_waitcnt vmcnt(0)" ::: "memory");
      __builtin_amdgcn_s_barrier();
      c = (c == 2) ? 0 : c + 1;
    }
  }
#undef STG

  // ---- epilogue ----  C/D layout (m89): col = lane&15, row = (lane>>4)*4 + reg
  const int crow = (lane >> 4) << 2;
  const int ccol = lane & 15;

  if (MODE == 1 && isphi) {
    #pragma unroll
    for (int m = 0; m < 8; ++m) {
      int gm = mt * 256 + wr * 128 + m * 16 + crow;
      #pragma unroll
      for (int n = 0; n < 4; ++n) {
        int gn = wc * 64 + n * 16 + ccol;
        if (gn < 192) {
          #pragma unroll
          for (int r = 0; r < 4; ++r)
            phiq[(size_t)kq * SINOFF + (size_t)(gm + r) * 192 + gn] = acc[m][n][r];
        }
      }
    }
    return;
  }

  #pragma unroll
  for (int m = 0; m < 8; ++m) {
    int gm = mt * 256 + wr * 128 + m * 16 + crow;
    #pragma unroll
    for (int n = 0; n < 4; ++n) {
      int gn = nt * 256 + wc * 64 + n * 16 + ccol;
      #pragma unroll
      for (int r = 0; r < 4; ++r)
        C[(size_t)(gm + r) * 2048 + gn] = acc[m][n][r];
    }
  }

  if (MODE == 1) {
    // fused RMSNorm sumsq: per-row sum of squares across this block's 256 cols -> atomicAdd
    __syncthreads();                       // all ds_reads done; LDS reusable
    float* red = (float*)ldsb;             // [256][4]
    #pragma unroll
    for (int m = 0; m < 8; ++m)
      #pragma unroll
      for (int r = 0; r < 4; ++r) {
        float s = 0.f;
        #pragma unroll
        for (int n = 0; n < 4; ++n) { float v = acc[m][n][r]; s += v * v; }
        s += __shfl_xor(s, 1); s += __shfl_xor(s, 2);
        s += __shfl_xor(s, 4); s += __shfl_xor(s, 8);
        if ((lane & 15) == 0)
          red[(wr * 128 + m * 16 + crow + r) * 4 + wc] = s;
      }
    __syncthreads();
    if (tid < 256) {
      float s = red[tid * 4] + red[tid * 4 + 1] + red[tid * 4 + 2] + red[tid * 4 + 3];
      atomicAdd(&sumsq[mt * 256 + tid], s);
    }
  }
}

// ---------------- phi: sum split-K partials + RMSNorm(192) + trig table (t-linear) ----------------
__global__ __launch_bounds__(64)
void phi_pass(const float* __restrict__ phiq, float* __restrict__ trig) {
  const int row = blockIdx.x;  // b*4096 + t
  const int tid = threadIdx.x;
  const float* p0 = phiq + (size_t)row * 192;
  float v0 = 0.f, v1 = 0.f, v2 = 0.f;
  #pragma unroll
  for (int kq = 0; kq < 4; ++kq) {
    const float* p = p0 + (size_t)kq * SINOFF;
    v0 += p[tid]; v1 += p[tid + 64]; v2 += p[tid + 128];
  }
  float ss = v0 * v0 + v1 * v1 + v2 * v2;
  #pragma unroll
  for (int o = 32; o > 0; o >>= 1) ss += __shfl_down(ss, o);
  ss = __shfl(ss, 0);
  const float sc = rsqrtf(ss * (1.0f / 192.0f) + EPSF);
  const int b = row >> 12, t = row & 4095;
  float v[3] = {v0, v1, v2};
  #pragma unroll
  for (int j = 0; j < 3; ++j) {
    int e = j * 64 + tid;
    int l = e >> 4, h = e & 15;
    float ph = v[j] * sc;
    float cs = __cosf(ph), sn = __sinf(ph);
    size_t idx = ((size_t)((b * 16 + h) * 12 + l)) * 4096 + t;
    trig[idx] = cs; trig[idx + SINOFF] = sn;
  }
}

// ---------------- butterfly levels 0..5: t-chunks with 63-row halo ----------------
__global__ __launch_bounds__(512)
void butterflyA(const float* __restrict__ in, u16* __restrict__ outb,
                const float* __restrict__ trig, const float* __restrict__ sumsq) {
  __shared__ float L[512 * 32];
  const int tc = blockIdx.x, ec = blockIdx.y, b = blockIdx.z;
  const int tid = threadIdx.x;
  const int t0 = tc * 449;
  const int e0 = ec * 32;
  const int h = e0 >> 7;
  const int pr = tid >> 3;
  const int c4 = (tid & 7) << 2;

  #pragma unroll
  for (int s = 0; s < 8; ++s) {
    int p = pr + s * 64;
    int t = t0 - 63 + p;
    float4 v = make_float4(0.f, 0.f, 0.f, 0.f);
    if (t >= 0 && t < 4096) {
      v = *(const float4*)&in[((size_t)(b * 4096 + t)) * 2048 + e0 + c4];
      float scl = rsqrtf(sumsq[b * 4096 + t] * (1.0f / 2048.0f) + EPSF);
      v.x *= scl; v.y *= scl; v.z *= scl; v.w *= scl;
    }
    *(float4*)&L[p * 32 + c4] = v;
  }
  __syncthreads();

  for (int l = 0; l < 6; ++l) {
    const int step = 1 << l;
    const float* cosT = trig + ((size_t)((b * 16 + h) * 12 + l)) * 4096;
    float4 nv[8];
    #pragma unroll
    for (int s = 0; s < 8; ++s) {
      int p = pr + s * 64;
      int t = t0 - 63 + p;
      float4 cur = *(const float4*)&L[p * 32 + c4];
      float4 prev = make_float4(0.f, 0.f, 0.f, 0.f);
      if (p >= step) prev = *(const float4*)&L[(p - step) * 32 + c4];
      float cs = 0.f, sn = 0.f;
      if (t >= 0 && t < 4096) { cs = cosT[t]; sn = cosT[SINOFF + t]; }
      nv[s].x = (cs * cur.x + sn * prev.x) * INV_SQRT2;
      nv[s].y = (cs * cur.y + sn * prev.y) * INV_SQRT2;
      nv[s].z = (cs * cur.z + sn * prev.z) * INV_SQRT2;
      nv[s].w = (cs * cur.w + sn * prev.w) * INV_SQRT2;
    }
    __syncthreads();
    #pragma unroll
    for (int s = 0; s < 8; ++s) {
      int p = pr + s * 64;
      *(float4*)&L[p * 32 + c4] = nv[s];
    }
    __syncthreads();
  }

  #pragma unroll
  for (int s = 0; s < 8; ++s) {
    int p = pr + s * 64;
    int t = t0 - 63 + p;
    if (p >= 63 && t < 4096) {
      float4 v = *(const float4*)&L[p * 32 + c4];
      uint32_t a = f2bf_rne(v.x), bb = f2bf_rne(v.y), c = f2bf_rne(v.z), d = f2bf_rne(v.w);
      uint2 o;
      o.x = a | (bb << 16);
      o.y = c | (d << 16);
      *(uint2*)&outb[((size_t)(b * 4096 + t)) * 2048 + e0 + c4] = o;
    }
  }
}

// ---------------- butterfly levels 6..11: fixed (r,h), q=0..63, no halo ----------------
__global__ __launch_bounds__(256)
void butterflyB(const u16* __restrict__ in, u16* __restrict__ outb,
                const float* __restrict__ trig) {
  __shared__ float L[64 * 128];
  const int r = blockIdx.x, h = blockIdx.y, b = blockIdx.z;
  const int tid = threadIdx.x;
  const int qr = tid >> 5;
  const int d4 = (tid & 31) << 2;

  #pragma unroll
  for (int s = 0; s < 8; ++s) {
    int q = qr + s * 8;
    int t = q * 64 + r;
    uint2 o = *(const uint2*)&in[((size_t)(b * 4096 + t)) * 2048 + h * 128 + d4];
    float4 v;
    v.x = __uint_as_float((o.x & 0xffffu) << 16);
    v.y = __uint_as_float(o.x & 0xffff0000u);
    v.z = __uint_as_float((o.y & 0xffffu) << 16);
    v.w = __uint_as_float(o.y & 0xffff0000u);
    *(float4*)&L[q * 128 + d4] = v;
  }
  __syncthreads();

  for (int l = 0; l < 6; ++l) {
    const int qs = 1 << l;
    const float* cosT = trig + ((size_t)((b * 16 + h) * 12 + 6 + l)) * 4096 + r;
    float4 nv[8];
    #pragma unroll
    for (int s = 0; s < 8; ++s) {
      int q = qr + s * 8;
      float4 cur = *(const float4*)&L[q * 128 + d4];
      float4 prev = make_float4(0.f, 0.f, 0.f, 0.f);
      if (q >= qs) prev = *(const float4*)&L[(q - qs) * 128 + d4];
      float cs = cosT[q << 6], sn = cosT[SINOFF + (q << 6)];
      nv[s].x = (cs * cur.x + sn * prev.x) * INV_SQRT2;
      nv[s].y = (cs * cur.y + sn * prev.y) * INV_SQRT2;
      nv[s].z = (cs * cur.z + sn * prev.z) * INV_SQRT2;
      nv[s].w = (cs * cur.w + sn * prev.w) * INV_SQRT2;
    }
    __syncthreads();
    #pragma unroll
    for (int s = 0; s < 8; ++s) {
      int q = qr + s * 8;
      *(float4*)&L[q * 128 + d4] = nv[s];
    }
    __syncthreads();
  }

  #pragma unroll
  for (int s = 0; s < 8; ++s) {
    int q = qr + s * 8;
    int t = q * 64 + r;
    float4 v = *(const float4*)&L[q * 128 + d4];
    uint32_t a = f2bf_rne(v.x), bb = f2bf_rne(v.y), c = f2bf_rne(v.z), d = f2bf_rne(v.w);
    uint2 o;
    o.x = a | (bb << 16);
    o.y = c | (d << 16);
    *(uint2*)&outb[((size_t)(b * 4096 + t)) * 2048 + h * 128 + d4] = o;
  }
}

// ---------------- launch ----------------
extern "C" void kernel_launch(void* const* d_in, const int* in_sizes, int n_in,
                              void* d_out, int out_size, void* d_ws, size_t ws_size,
                              hipStream_t stream) {
  const float* x    = (const float*)d_in[0];
  const float* Wtok = (const float*)d_in[1];
  const float* Wlvl = (const float*)d_in[2];
  const float* Wout = (const float*)d_in[3];

  char* ws = (char*)d_ws;
  u16*   xb     = (u16*)(ws + OFF_XB);
  u16*   wcat   = (u16*)(ws + OFF_WCAT);
  u16*   woutb  = (u16*)(ws + OFF_WOUT);
  u16*   thA    = (u16*)(ws + OFF_XB);     // alias: x bf16 dead after gemm1
  u16*   thB    = (u16*)(ws + OFF_THBF);   // theta_final (overwrites dead phiq)
  float* phiq   = (float*)(ws + OFF_THBF); // split-K phi partials (dead after phi_pass)
  float* trig   = (float*)(ws + OFF_TRIG);
  float* sumsq  = (float*)(ws + OFF_SSQ);
  float* out    = (float*)d_out;

  // 0. zero sumsq (8192 f32)
  zero_f32<<<8, 256, 0, stream>>>((float4*)sumsq, 2048);

  // 1. casts f32 -> bf16 (wcat pad rows 2240..2303 stay 0xAA garbage: benign bf16, outputs discarded)
  cast_f32_bf16<<<2048, 256, 0, stream>>>(x, xb, 4194304);
  cast_f32_bf16<<<1024, 256, 0, stream>>>(Wtok, wcat, 1048576);
  cast_f32_bf16<<<384, 256, 0, stream>>>(Wlvl, wcat + (size_t)2048 * 2048, 98304);
  cast_f32_bf16<<<1024, 256, 0, stream>>>(Wout, woutb, 1048576);

  // 2. GEMM1: 256 theta-blocks (full K, sumsq fused) + 128 phi-blocks (split-K/4) = 384
  gemm8<1><<<384, 512, 0, stream>>>(xb, wcat, out, phiq, sumsq, 384);

  // 3. phi: sum partials + RMSNorm + trig tables
  phi_pass<<<8192, 64, 0, stream>>>(phiq, trig);

  // 4. butterfly levels 0..5 (f32 theta_raw + fused rmsnorm scale -> bf16)
  butterflyA<<<dim3(10, 64, 2), 512, 0, stream>>>(out, thA, trig, sumsq);

  // 5. butterfly levels 6..11
  butterflyB<<<dim3(64, 16, 2), 256, 0, stream>>>(thA, thB, trig);

  // 6. GEMM3: theta_final x W_out^T -> d_out (256 blocks = 1 full CU round)
  gemm8<0><<<256, 512, 0, stream>>>(thB, woutb, out, nullptr, nullptr, 256);
}

// Round 5
// 441.689 us; speedup vs baseline: 1.0898x; 1.0450x over previous
//
#include <hip/hip_runtime.h>
#include <cstdint>

typedef unsigned short u16;
typedef short bh8 __attribute__((ext_vector_type(8)));
typedef float f32x4 __attribute__((ext_vector_type(4)));

#define EPSF 1.1920929e-07f
#define INV_SQRT2 0.70710678118654752440f
#define SINOFF 1572864

// ---------------- workspace layout (bytes) — exactly round-1's proven 103809024 ----------------
static constexpr size_t OFF_XB   = 0;                        // x bf16 33554432; later thetaA bf16
static constexpr size_t OFF_WCAT = 33554432;                 // [2304][2048] bf16 = 9437184
static constexpr size_t OFF_SC   = OFF_WCAT + 9175040;       // scales (32KB) inside wcat pad rows 2240+ (dead after GEMM1)
static constexpr size_t OFF_WOUT = OFF_WCAT + 9437184;       // 8388608
static constexpr size_t OFF_THBF = OFF_WOUT + 8388608;       // 33554432 theta_final bf16
static constexpr size_t OFF_PHI  = OFF_THBF + 33554432;      // 6291456 phiraw [8192][192] f32
static constexpr size_t OFF_TRIG = OFF_PHI + 6291456;        // 12582912 (cos 1572864 f32 + sin)
// end = 103809024

// ---------------- helpers ----------------
__device__ __forceinline__ uint32_t f2bf_rne(float f) {
  uint32_t u = __float_as_uint(f);
  u += 0x7fffu + ((u >> 16) & 1u);
  return u >> 16;
}

__device__ __forceinline__ void gload_lds16(const void* g, void* l) {
  __builtin_amdgcn_global_load_lds(
      (const __attribute__((address_space(1))) void*)g,
      (__attribute__((address_space(3))) void*)l, 16, 0, 0);
}

// ---------------- cast f32 -> bf16 ----------------
__global__ __launch_bounds__(256)
void cast_f32_bf16(const float* __restrict__ src, u16* __restrict__ dst, int n4) {
  int i = blockIdx.x * blockDim.x + threadIdx.x;
  int stride = gridDim.x * blockDim.x;
  for (; i < n4; i += stride) {
    float4 v = ((const float4*)src)[i];
    uint32_t a = __float_as_uint(v.x); a += 0x7fffu + ((a >> 16) & 1u);
    uint32_t b = __float_as_uint(v.y); b += 0x7fffu + ((b >> 16) & 1u);
    uint32_t c = __float_as_uint(v.z); c += 0x7fffu + ((c >> 16) & 1u);
    uint32_t d = __float_as_uint(v.w); d += 0x7fffu + ((d >> 16) & 1u);
    uint2 o;
    o.x = (a >> 16) | (b & 0xffff0000u);
    o.y = (c >> 16) | (d & 0xffff0000u);
    ((uint2*)dst)[i] = o;
  }
}

// ---------------- round-1 GEMM (proven 135us): 128x128 tile, BK=64, 4 waves ----------------
template<int SPLIT>
__global__ __launch_bounds__(256)
void gemm_bt(const u16* __restrict__ A, const u16* __restrict__ B,
             float* __restrict__ C0, float* __restrict__ C1,
             int K, int ntiles) {
  __shared__ u16 As[128 * 64];
  __shared__ u16 Bs[128 * 64];
  const int tid  = threadIdx.x;
  const int w    = tid >> 6;
  const int lane = tid & 63;
  const int mt = blockIdx.x / ntiles, nt = blockIdx.x % ntiles;
  const int wm = (w >> 1) << 6, wn = (w & 1) << 6;
  const int Kb = K * 2;

  const char* Ab = (const char*)(A + (size_t)mt * 128 * K);
  const char* Bb = (const char*)(B + (size_t)nt * 128 * K);
  char* AsB = (char*)As;
  char* BsB = (char*)Bs;

  const int srow  = w * 8 + (lane >> 3);
  const int scolb = (lane & 7) << 4;

  f32x4 acc[4][4] = {};

  for (int kt = 0; kt < K; kt += 64) {
    #pragma unroll
    for (int i = 0; i < 4; ++i) {
      int row = i * 32 + srow;
      int src = scolb ^ ((row & 7) << 4);
      gload_lds16(Ab + (size_t)row * Kb + kt * 2 + src, AsB + i * 4096 + w * 1024);
      gload_lds16(Bb + (size_t)row * Kb + kt * 2 + src, BsB + i * 4096 + w * 1024);
    }
    __syncthreads();
    #pragma unroll
    for (int kk = 0; kk < 2; ++kk) {
      const int kbyte = kk * 64 + ((lane >> 4) << 4);
      bh8 af[4], bfr[4];
      #pragma unroll
      for (int m = 0; m < 4; ++m) {
        int ar = wm + m * 16 + (lane & 15);
        af[m] = *(const bh8*)(AsB + ar * 128 + (kbyte ^ ((ar & 7) << 4)));
        int br = wn + m * 16 + (lane & 15);
        bfr[m] = *(const bh8*)(BsB + br * 128 + (kbyte ^ ((br & 7) << 4)));
      }
      #pragma unroll
      for (int m = 0; m < 4; ++m)
        #pragma unroll
        for (int n = 0; n < 4; ++n)
          acc[m][n] = __builtin_amdgcn_mfma_f32_16x16x32_bf16(af[m], bfr[n], acc[m][n], 0, 0, 0);
    }
    __syncthreads();
  }

  const int crow0 = mt * 128 + wm + ((lane >> 4) << 2);
  const int ccol0 = nt * 128 + wn + (lane & 15);
  #pragma unroll
  for (int m = 0; m < 4; ++m) {
    #pragma unroll
    for (int n = 0; n < 4; ++n) {
      int gn = ccol0 + n * 16;
      #pragma unroll
      for (int r = 0; r < 4; ++r) {
        int gm = crow0 + m * 16 + r;
        if (SPLIT) {
          if (gn < 2048)      C0[(size_t)gm * 2048 + gn] = acc[m][n][r];
          else if (gn < 2240) C1[(size_t)gm * 192 + (gn - 2048)] = acc[m][n][r];
        } else {
          C0[(size_t)gm * 2048 + gn] = acc[m][n][r];
        }
      }
    }
  }
}

// ---------------- 8-phase 256x256/BK=64 GEMM (m201-style port) for GEMM3 ----------------
// 8 waves (2M x 4N), per-wave 128x64 out. LDS 128KB: A[2buf][16RB][2kk][1024B], B same at +64KB.
// Per K-tile: 4 phases, each {ds_reads for quadrant | stage one 16KB half-panel | bar | 16 MFMA | bar}.
// Stagger: ph1->B-h0(t+1), ph2->B-h1(t+1), ph3->A-h0(t+2), ph4->A-h1(t+2); boundary vmcnt(4).
// A halves read ph1-2 only; B halves read ph1&3 -> every stage lands after its region's reads + barrier.
__global__ __launch_bounds__(512, 1)
void gemm256(const u16* __restrict__ A, const u16* __restrict__ B,
             float* __restrict__ C, int ntiles, int nwg) {
  __shared__ __align__(16) char lds[131072];
  const int tid = threadIdx.x;
  const int w = tid >> 6, lane = tid & 63;
  const int wr = w >> 2, wc = w & 3;
  const int cpx = nwg >> 3;
  const int wg = ((int)blockIdx.x & 7) * cpx + ((int)blockIdx.x >> 3);
  const int mt = wg / ntiles, nt = wg % ntiles;

  const char* Ab = (const char*)A + (size_t)mt * 256 * 4096;
  const char* Bb = (const char*)B + (size_t)nt * 256 * 4096;
  // per-lane staging source base: row (lane&15), k-chunk (lane>>4); wave handles rows w*16..+15
  const char* pA = Ab + (lane & 15) * 4096 + (lane >> 4) * 16 + (size_t)w * 16 * 4096;
  const char* pB = Bb + (lane & 15) * 4096 + (lane >> 4) * 16 + (size_t)w * 16 * 4096;
  char* ldsA = lds;
  char* ldsB = lds + 65536;
  const int wst = w * 2048;
  const int lo16 = lane * 16;

#define STGA(tt, h, b) do { \
    gload_lds16(pA + (h) * 524288 + (tt) * 128,      ldsA + (b) * 32768 + (h) * 16384 + wst); \
    gload_lds16(pA + (h) * 524288 + (tt) * 128 + 64, ldsA + (b) * 32768 + (h) * 16384 + wst + 1024); } while (0)
#define STGB(tt, h, b) do { \
    gload_lds16(pB + (h) * 524288 + (tt) * 128,      ldsB + (b) * 32768 + (h) * 16384 + wst); \
    gload_lds16(pB + (h) * 524288 + (tt) * 128 + 64, ldsB + (b) * 32768 + (h) * 16384 + wst + 1024); } while (0)

  f32x4 acc[8][4] = {};
  bh8 amlo[4][2], amhi[4][2], bnlo[2][2], bnhi[2][2];

  // prologue: tile0 fully + tile1 A-halves; wait tile0 landed (keep 4 newest in flight)
  STGA(0, 0, 0); STGA(0, 1, 0); STGB(0, 0, 0); STGB(0, 1, 0);
  STGA(1, 0, 1); STGA(1, 1, 1);
  asm volatile("s_waitcnt vmcnt(4)" ::: "memory");
  __builtin_amdgcn_s_barrier();

  for (int t = 0; t < 32; ++t) {
    const int c = t & 1, d = c ^ 1;
    const char* Abase = ldsA + c * 32768 + wr * 16384;  // wave's A-half (8 RBs)
    const char* Bbase = ldsB + c * 32768 + wc * 8192;   // wave's 4 CBs

    // ---- phase 1: read A-lo + B-lo | stage B-h0(t+1) | mlo x nlo ----
    #pragma unroll
    for (int m = 0; m < 4; ++m)
      #pragma unroll
      for (int kk = 0; kk < 2; ++kk)
        amlo[m][kk] = *(const bh8*)(Abase + m * 2048 + kk * 1024 + lo16);
    #pragma unroll
    for (int n = 0; n < 2; ++n)
      #pragma unroll
      for (int kk = 0; kk < 2; ++kk)
        bnlo[n][kk] = *(const bh8*)(Bbase + n * 2048 + kk * 1024 + lo16);
    if (t + 1 < 32) STGB(t + 1, 0, d);
    __builtin_amdgcn_s_barrier();
    __builtin_amdgcn_s_setprio(1);
    #pragma unroll
    for (int m = 0; m < 4; ++m)
      #pragma unroll
      for (int n = 0; n < 2; ++n)
        #pragma unroll
        for (int kk = 0; kk < 2; ++kk)
          acc[m][n] = __builtin_amdgcn_mfma_f32_16x16x32_bf16(amlo[m][kk], bnlo[n][kk], acc[m][n], 0, 0, 0);
    __builtin_amdgcn_s_setprio(0);
    __builtin_amdgcn_s_barrier();

    // ---- phase 2: read A-hi | stage B-h1(t+1) | mhi x nlo ----
    #pragma unroll
    for (int m = 0; m < 4; ++m)
      #pragma unroll
      for (int kk = 0; kk < 2; ++kk)
        amhi[m][kk] = *(const bh8*)(Abase + (m + 4) * 2048 + kk * 1024 + lo16);
    if (t + 1 < 32) STGB(t + 1, 1, d);
    __builtin_amdgcn_s_barrier();
    __builtin_amdgcn_s_setprio(1);
    #pragma unroll
    for (int m = 0; m < 4; ++m)
      #pragma unroll
      for (int n = 0; n < 2; ++n)
        #pragma unroll
        for (int kk = 0; kk < 2; ++kk)
          acc[m + 4][n] = __builtin_amdgcn_mfma_f32_16x16x32_bf16(amhi[m][kk], bnlo[n][kk], acc[m + 4][n], 0, 0, 0);
    __builtin_amdgcn_s_setprio(0);
    __builtin_amdgcn_s_barrier();

    // ---- phase 3: read B-hi | stage A-h0(t+2) into buf c (A reads of c finished ph2) | mhi x nhi ----
    #pragma unroll
    for (int n = 0; n < 2; ++n)
      #pragma unroll
      for (int kk = 0; kk < 2; ++kk)
        bnhi[n][kk] = *(const bh8*)(Bbase + (n + 2) * 2048 + kk * 1024 + lo16);
    if (t + 2 < 32) STGA(t + 2, 0, c);
    __builtin_amdgcn_s_barrier();
    __builtin_amdgcn_s_setprio(1);
    #pragma unroll
    for (int m = 0; m < 4; ++m)
      #pragma unroll
      for (int n = 0; n < 2; ++n)
        #pragma unroll
        for (int kk = 0; kk < 2; ++kk)
          acc[m + 4][n + 2] = __builtin_amdgcn_mfma_f32_16x16x32_bf16(amhi[m][kk], bnhi[n][kk], acc[m + 4][n + 2], 0, 0, 0);
    __builtin_amdgcn_s_setprio(0);
    __builtin_amdgcn_s_barrier();

    // ---- phase 4: stage A-h1(t+2) | mlo x nhi | boundary vmcnt ----
    if (t + 2 < 32) STGA(t + 2, 1, c);
    __builtin_amdgcn_s_barrier();
    __builtin_amdgcn_s_setprio(1);
    #pragma unroll
    for (int m = 0; m < 4; ++m)
      #pragma unroll
      for (int n = 0; n < 2; ++n)
        #pragma unroll
        for (int kk = 0; kk < 2; ++kk)
          acc[m][n + 2] = __builtin_amdgcn_mfma_f32_16x16x32_bf16(amlo[m][kk], bnhi[n][kk], acc[m][n + 2], 0, 0, 0);
    __builtin_amdgcn_s_setprio(0);
    if (t < 30) asm volatile("s_waitcnt vmcnt(4)" ::: "memory");
    else        asm volatile("s_waitcnt vmcnt(0)" ::: "memory");
    __builtin_amdgcn_s_barrier();
  }
#undef STGA
#undef STGB

  // epilogue: C/D layout (m89): col = lane&15, row = (lane>>4)*4 + reg
  const int crow = (lane >> 4) << 2;
  const int ccol = lane & 15;
  #pragma unroll
  for (int m = 0; m < 8; ++m) {
    int gm = mt * 256 + wr * 128 + m * 16 + crow;
    #pragma unroll
    for (int n = 0; n < 4; ++n) {
      int gn = nt * 256 + wc * 64 + n * 16 + ccol;
      #pragma unroll
      for (int r = 0; r < 4; ++r)
        C[(size_t)(gm + r) * 2048 + gn] = acc[m][n][r];
    }
  }
}

// ---------------- RMSNorm scales only (row of 2048 f32 -> 1 f32 scale) ----------------
__global__ __launch_bounds__(256)
void rmsnorm_scales(const float* __restrict__ th, float* __restrict__ sc) {
  const int row = blockIdx.x;
  const int tid = threadIdx.x;
  const float* p = th + (size_t)row * 2048;
  float4 a = ((const float4*)p)[tid];
  float4 b = ((const float4*)p)[tid + 256];
  float ss = a.x*a.x + a.y*a.y + a.z*a.z + a.w*a.w
           + b.x*b.x + b.y*b.y + b.z*b.z + b.w*b.w;
  #pragma unroll
  for (int o = 32; o > 0; o >>= 1) ss += __shfl_down(ss, o);
  __shared__ float red[4];
  if ((tid & 63) == 0) red[tid >> 6] = ss;
  __syncthreads();
  if (tid == 0) {
    float tot = red[0] + red[1] + red[2] + red[3];
    sc[row] = rsqrtf(tot * (1.0f / 2048.0f) + EPSF);
  }
}

// ---------------- phi: RMSNorm(192) + cos/sin table (t-linear, 12 levels) ----------------
__global__ __launch_bounds__(64)
void phi_pass(const float* __restrict__ phiraw, float* __restrict__ trig) {
  const int row = blockIdx.x;  // b*4096 + t
  const int tid = threadIdx.x;
  const float* pr = phiraw + (size_t)row * 192;
  float v0 = pr[tid], v1 = pr[tid + 64], v2 = pr[tid + 128];
  float ss = v0 * v0 + v1 * v1 + v2 * v2;
  #pragma unroll
  for (int o = 32; o > 0; o >>= 1) ss += __shfl_down(ss, o);
  ss = __shfl(ss, 0);
  const float sc = rsqrtf(ss * (1.0f / 192.0f) + EPSF);
  const int b = row >> 12, t = row & 4095;
  float v[3] = {v0, v1, v2};
  #pragma unroll
  for (int j = 0; j < 3; ++j) {
    int e = j * 64 + tid;
    int l = e >> 4, h = e & 15;
    float ph = v[j] * sc;
    float cs = __cosf(ph), sn = __sinf(ph);
    size_t idx = ((size_t)((b * 16 + h) * 12 + l)) * 4096 + t;
    trig[idx] = cs; trig[idx + SINOFF] = sn;
  }
}

// ---------------- butterfly levels 0..5: t-chunks with 63-row halo (scale on load) ----------------
__global__ __launch_bounds__(512)
void butterflyA(const float* __restrict__ in, u16* __restrict__ outb,
                const float* __restrict__ trig, const float* __restrict__ scales) {
  __shared__ float L[512 * 32];
  const int tc = blockIdx.x, ec = blockIdx.y, b = blockIdx.z;
  const int tid = threadIdx.x;
  const int t0 = tc * 449;
  const int e0 = ec * 32;
  const int h = e0 >> 7;
  const int pr = tid >> 3;
  const int c4 = (tid & 7) << 2;

  #pragma unroll
  for (int s = 0; s < 8; ++s) {
    int p = pr + s * 64;
    int t = t0 - 63 + p;
    float4 v = make_float4(0.f, 0.f, 0.f, 0.f);
    if (t >= 0 && t < 4096) {
      v = *(const float4*)&in[((size_t)(b * 4096 + t)) * 2048 + e0 + c4];
      float scl = scales[b * 4096 + t];
      v.x *= scl; v.y *= scl; v.z *= scl; v.w *= scl;
    }
    *(float4*)&L[p * 32 + c4] = v;
  }
  __syncthreads();

  for (int l = 0; l < 6; ++l) {
    const int step = 1 << l;
    const float* cosT = trig + ((size_t)((b * 16 + h) * 12 + l)) * 4096;
    float4 nv[8];
    #pragma unroll
    for (int s = 0; s < 8; ++s) {
      int p = pr + s * 64;
      int t = t0 - 63 + p;
      float4 cur = *(const float4*)&L[p * 32 + c4];
      float4 prev = make_float4(0.f, 0.f, 0.f, 0.f);
      if (p >= step) prev = *(const float4*)&L[(p - step) * 32 + c4];
      float cs = 0.f, sn = 0.f;
      if (t >= 0 && t < 4096) { cs = cosT[t]; sn = cosT[SINOFF + t]; }
      nv[s].x = (cs * cur.x + sn * prev.x) * INV_SQRT2;
      nv[s].y = (cs * cur.y + sn * prev.y) * INV_SQRT2;
      nv[s].z = (cs * cur.z + sn * prev.z) * INV_SQRT2;
      nv[s].w = (cs * cur.w + sn * prev.w) * INV_SQRT2;
    }
    __syncthreads();
    #pragma unroll
    for (int s = 0; s < 8; ++s) {
      int p = pr + s * 64;
      *(float4*)&L[p * 32 + c4] = nv[s];
    }
    __syncthreads();
  }

  #pragma unroll
  for (int s = 0; s < 8; ++s) {
    int p = pr + s * 64;
    int t = t0 - 63 + p;
    if (p >= 63 && t < 4096) {
      float4 v = *(const float4*)&L[p * 32 + c4];
      uint32_t a = f2bf_rne(v.x), bb = f2bf_rne(v.y), c = f2bf_rne(v.z), d = f2bf_rne(v.w);
      uint2 o;
      o.x = a | (bb << 16);
      o.y = c | (d << 16);
      *(uint2*)&outb[((size_t)(b * 4096 + t)) * 2048 + e0 + c4] = o;
    }
  }
}

// ---------------- butterfly levels 6..11: fixed (r,h), q=0..63, no halo ----------------
__global__ __launch_bounds__(256)
void butterflyB(const u16* __restrict__ in, u16* __restrict__ outb,
                const float* __restrict__ trig) {
  __shared__ float L[64 * 128];
  const int r = blockIdx.x, h = blockIdx.y, b = blockIdx.z;
  const int tid = threadIdx.x;
  const int qr = tid >> 5;
  const int d4 = (tid & 31) << 2;

  #pragma unroll
  for (int s = 0; s < 8; ++s) {
    int q = qr + s * 8;
    int t = q * 64 + r;
    uint2 o = *(const uint2*)&in[((size_t)(b * 4096 + t)) * 2048 + h * 128 + d4];
    float4 v;
    v.x = __uint_as_float((o.x & 0xffffu) << 16);
    v.y = __uint_as_float(o.x & 0xffff0000u);
    v.z = __uint_as_float((o.y & 0xffffu) << 16);
    v.w = __uint_as_float(o.y & 0xffff0000u);
    *(float4*)&L[q * 128 + d4] = v;
  }
  __syncthreads();

  for (int l = 0; l < 6; ++l) {
    const int qs = 1 << l;
    const float* cosT = trig + ((size_t)((b * 16 + h) * 12 + 6 + l)) * 4096 + r;
    float4 nv[8];
    #pragma unroll
    for (int s = 0; s < 8; ++s) {
      int q = qr + s * 8;
      float4 cur = *(const float4*)&L[q * 128 + d4];
      float4 prev = make_float4(0.f, 0.f, 0.f, 0.f);
      if (q >= qs) prev = *(const float4*)&L[(q - qs) * 128 + d4];
      float cs = cosT[q << 6], sn = cosT[SINOFF + (q << 6)];
      nv[s].x = (cs * cur.x + sn * prev.x) * INV_SQRT2;
      nv[s].y = (cs * cur.y + sn * prev.y) * INV_SQRT2;
      nv[s].z = (cs * cur.z + sn * prev.z) * INV_SQRT2;
      nv[s].w = (cs * cur.w + sn * prev.w) * INV_SQRT2;
    }
    __syncthreads();
    #pragma unroll
    for (int s = 0; s < 8; ++s) {
      int q = qr + s * 8;
      *(float4*)&L[q * 128 + d4] = nv[s];
    }
    __syncthreads();
  }

  #pragma unroll
  for (int s = 0; s < 8; ++s) {
    int q = qr + s * 8;
    int t = q * 64 + r;
    float4 v = *(const float4*)&L[q * 128 + d4];
    uint32_t a = f2bf_rne(v.x), bb = f2bf_rne(v.y), c = f2bf_rne(v.z), d = f2bf_rne(v.w);
    uint2 o;
    o.x = a | (bb << 16);
    o.y = c | (d << 16);
    *(uint2*)&outb[((size_t)(b * 4096 + t)) * 2048 + h * 128 + d4] = o;
  }
}

// ---------------- launch ----------------
extern "C" void kernel_launch(void* const* d_in, const int* in_sizes, int n_in,
                              void* d_out, int out_size, void* d_ws, size_t ws_size,
                              hipStream_t stream) {
  const float* x    = (const float*)d_in[0];
  const float* Wtok = (const float*)d_in[1];
  const float* Wlvl = (const float*)d_in[2];
  const float* Wout = (const float*)d_in[3];

  char* ws = (char*)d_ws;
  u16*   xb     = (u16*)(ws + OFF_XB);
  u16*   wcat   = (u16*)(ws + OFF_WCAT);
  u16*   woutb  = (u16*)(ws + OFF_WOUT);
  u16*   thA    = (u16*)(ws + OFF_XB);     // alias: x bf16 dead after gemm1
  u16*   thB    = (u16*)(ws + OFF_THBF);
  float* scales = (float*)(ws + OFF_SC);   // inside wcat pad rows (dead after gemm1)
  float* phiraw = (float*)(ws + OFF_PHI);
  float* trig   = (float*)(ws + OFF_TRIG);
  float* out    = (float*)d_out;

  // 1. casts f32 -> bf16 (wcat pad rows 2240+ stay 0xAA garbage: tiny bf16 values, outputs discarded)
  cast_f32_bf16<<<2048, 256, 0, stream>>>(x, xb, 4194304);
  cast_f32_bf16<<<1024, 256, 0, stream>>>(Wtok, wcat, 1048576);
  cast_f32_bf16<<<384, 256, 0, stream>>>(Wlvl, wcat + (size_t)2048 * 2048, 98304);
  cast_f32_bf16<<<1024, 256, 0, stream>>>(Wout, woutb, 1048576);

  // 2. GEMM1 (round-1 proven kernel): theta_raw (d_out f32) + phiraw
  gemm_bt<1><<<64 * 18, 256, 0, stream>>>(xb, wcat, out, phiraw, 2048, 18);

  // 3. RMSNorm scales (applied in butterflyA)
  rmsnorm_scales<<<8192, 256, 0, stream>>>(out, scales);

  // 4. phi: RMSNorm + trig tables
  phi_pass<<<8192, 64, 0, stream>>>(phiraw, trig);

  // 5. butterfly levels 0..5
  butterflyA<<<dim3(10, 64, 2), 512, 0, stream>>>(out, thA, trig, scales);

  // 6. butterfly levels 6..11
  butterflyB<<<dim3(64, 16, 2), 256, 0, stream>>>(thA, thB, trig);

  // 7. GEMM3 (new 8-phase template): theta_final x W_out^T -> d_out
  gemm256<<<256, 512, 0, stream>>>(thB, woutb, out, 8, 256);
}